// Round 8
// baseline (497.988 us; speedup 1.0000x reference)
//
#include <hip/hip_runtime.h>
#include <stdint.h>

typedef __attribute__((ext_vector_type(8))) short short8;
typedef __attribute__((ext_vector_type(4))) short short4v;
typedef __attribute__((ext_vector_type(4))) float float4v;
typedef __attribute__((ext_vector_type(2))) unsigned uint2v;

__device__ __forceinline__ float bf2f(short s) {
  union { unsigned u; float f; } x;
  x.u = ((unsigned)(unsigned short)s) << 16;
  return x.f;
}
__device__ __forceinline__ short f2bf(float f) {
  union { float f; unsigned u; } x;
  x.f = f;
  unsigned r = x.u + 0x7fffu + ((x.u >> 16) & 1u);
  return (short)(r >> 16);
}
// bare v_exp_f32 — exp2f() calls __ocml_exp2_f32 (range/denorm fixups, ~30
// VALU); our scores are bounded |s|<~50 so the raw HW op is exact.
__device__ __forceinline__ float fexp2(float x) {
#if __has_builtin(__builtin_amdgcn_exp2f)
  return __builtin_amdgcn_exp2f(x);
#else
  float r;
  asm("v_exp_f32 %0, %1" : "=v"(r) : "v"(x));
  return r;
#endif
}
__device__ __forceinline__ void glds16(const void* g, void* l) {
  __builtin_amdgcn_global_load_lds(
      (const __attribute__((address_space(1))) void*)g,
      (__attribute__((address_space(3))) void*)l, 16, 0, 0);
}
__device__ __forceinline__ void bar() { __builtin_amdgcn_s_barrier(); }

// ---------------------------------------------------------------------------
// fp32 transpose -> bf16: src (R x C, f32) -> dst (C x R, bf16), 64x64 tiles.
// ---------------------------------------------------------------------------
__device__ __forceinline__ void transpose_tile(
    const float* __restrict__ src, short* __restrict__ dst, int R, int C,
    int r0, int c0) {
  __shared__ short t[64 * 72];
  const int tid = threadIdx.x;
#pragma unroll
  for (int r = 0; r < 2; ++r) {
    int c = r * 256 + tid;
    int row = c >> 3, col8 = (c & 7) * 8;
    const float4v a = *(const float4v*)&src[(long)(r0 + row) * C + c0 + col8];
    const float4v b = *(const float4v*)&src[(long)(r0 + row) * C + c0 + col8 + 4];
    short8 v;
#pragma unroll
    for (int e = 0; e < 4; ++e) { v[e] = f2bf(a[e]); v[e + 4] = f2bf(b[e]); }
    *(short8*)&t[row * 72 + col8] = v;
  }
  __syncthreads();
#pragma unroll
  for (int r = 0; r < 2; ++r) {
    int c = r * 256 + tid;
    int orow = c >> 3, ocol8 = (c & 7) * 8;
    short8 w;
#pragma unroll
    for (int e = 0; e < 8; ++e) w[e] = t[(ocol8 + e) * 72 + orow];
    *(short8*)&dst[(long)(c0 + orow) * R + r0 + ocol8] = w;
  }
}

// ---------------------------------------------------------------------------
// Fused preprocessing: blocks [0,4096) X f32->bf16; [4096,7168) QKV W^T.
// ---------------------------------------------------------------------------
__global__ __launch_bounds__(256) void prep(
    const float* __restrict__ X, short* __restrict__ Xb,
    const float* __restrict__ Wq, const float* __restrict__ Wk,
    const float* __restrict__ Wv, short* __restrict__ WT) {
  const int id = blockIdx.x;
  if (id < 4096) {
    const long i = ((long)id * 256 + threadIdx.x) * 8;
    const float4v a = *(const float4v*)&X[i];
    const float4v b = *(const float4v*)&X[i + 4];
    short8 v;
#pragma unroll
    for (int e = 0; e < 4; ++e) { v[e] = f2bf(a[e]); v[e + 4] = f2bf(b[e]); }
    *(short8*)&Xb[i] = v;
  } else {
    const int r = id - 4096;
    const int z = r >> 10, bx = r & 31, by = (r >> 5) & 31;
    const float* src = z == 0 ? Wq : (z == 1 ? Wk : Wv);
    const int C = z == 0 ? 2048 : 512;
    if (bx * 64 < C) {
      short* dst = WT + (z == 0 ? 0 : (z == 1 ? 2048 * 2048 : 2560 * 2048));
      transpose_tile(src, dst, 2048, C, by * 64, bx * 64);
    }
  }
}

__global__ __launch_bounds__(256) void transpose_f2b(
    const float* __restrict__ src, short* __restrict__ dst, int R, int C) {
  transpose_tile(src, dst, R, C, blockIdx.y * 64, blockIdx.x * 64);
}

// ---------------------------------------------------------------------------
// V reshape+transpose: YV (B,S,ld) cols [col0, col0+512) bf16 -> Vt (B,G,64,S).
// grid: (S/64, B*G)
// ---------------------------------------------------------------------------
__global__ __launch_bounds__(256) void vtrans(const short* __restrict__ Y,
                                              short* __restrict__ Vt,
                                              int ld, int col0) {
  const int bg = blockIdx.y;
  const int b = bg >> 3, gk = bg & 7;
  const int s0 = blockIdx.x * 64;
  __shared__ short t[64 * 72];
  const int tid = threadIdx.x;
#pragma unroll
  for (int r = 0; r < 2; ++r) {
    int c = r * 256 + tid;
    int row = c >> 3, col8 = (c & 7) * 8;
    short8 v = *(const short8*)&Y[(long)(b * 2048 + s0 + row) * ld + col0 + gk * 64 + col8];
    *(short8*)&t[row * 72 + col8] = v;
  }
  __syncthreads();
#pragma unroll
  for (int r = 0; r < 2; ++r) {
    int c = r * 256 + tid;
    int d = c >> 3, s8 = (c & 7) * 8;
    short8 w;
#pragma unroll
    for (int e = 0; e < 8; ++e) w[e] = t[(s8 + e) * 72 + d];
    *(short8*)&Vt[((long)bg * 64 + d) * 2048 + s0 + s8] = w;
  }
}

// ---------------------------------------------------------------------------
// GEMM, 256x256 tile, BK=64, 8 waves (2M x 4N), guide-verified minimum
// 2-phase schedule (T3 recipe; m230-V0 = 682 TF refcheck'd):
//   per K-tile: stage t+1 into buf^1 -> ds_read buf -> MFMA -> vmcnt(0) ->
//   ONE barrier. (My r2-r4 4-phase had 10 barriers/tile = the ~390 TF bug.)
// Ledger: every ds_read of buf^1 in tile t-1 retires before its MFMA's
// compiler-inserted lgkmcnt wait, hence before t-1's barrier; the t stage
// into buf^1 therefore never overwrites a live read. vmcnt(0)+barrier at
// tile end = all DMA landed before any wave reads the new tile.
// Data layout (swizzle, staging offsets) copied verbatim from the r2-r4
// kernel that passed refcheck 3x. Epilogues from r5-r7 (proven).
// MODE 1: fused RoPE/layout epilogue (head = 64-col wave strip).
// MODE 2: plain f32 store.
// ---------------------------------------------------------------------------
template <int MODE>
__global__ __launch_bounds__(512, 1) void gemm2(
    const short* __restrict__ A, const short* __restrict__ BT,
    float* __restrict__ Cf, short* __restrict__ Qr, short* __restrict__ Kr,
    short* __restrict__ YV, const float* __restrict__ cosp,
    const float* __restrict__ sinp, int M, int N, int K) {
  (void)M;
  __shared__ short As[2][16384];  // [buf][256 rows x 64 cols]
  __shared__ short Bs[2][16384];
  const int tid = threadIdx.x;
  const int w = tid >> 6, lane = tid & 63;
  const int g = lane >> 4, lr = lane & 15;
  const int wm = w >> 2, wn = w & 3;
  const int m0 = blockIdx.y << 8, n0 = blockIdx.x << 8;

  // staging: thread row r0 = tid>>3, granule tid&7; source col pre-swizzled
  // with the same involution as the read (proven r2-r4).
  const int r0 = tid >> 3;
  const int scol = ((tid & 7) << 3) ^ (((r0 >> 2) & 1) << 4) ^ (((r0 >> 3) & 1) << 5);
  const long aoff = (long)(m0 + r0) * K + scol;
  const long boff = (long)(n0 + r0) * K + scol;

  // ds_read offsets (element units); row bits 2,3 of the 16-row MFMA block
  // are lr bits 2,3.
  const int swz = (((lr >> 2) & 1) << 4) | (((lr >> 3) & 1) << 5);
  const int acol0 = (g << 3) ^ swz;         // kk = 0
  const int acol1 = (32 + (g << 3)) ^ swz;  // kk = 1
  const int abase = (wm * 128 + lr) * 64;
  const int bbase = (wn * 64 + lr) * 64;

  float4v acc[8][4];
#pragma unroll
  for (int i = 0; i < 8; ++i)
#pragma unroll
    for (int j = 0; j < 4; ++j) acc[i][j] = (float4v)0.f;

#define STAGE_A(l, buf, kg)                                          \
  glds16(A + aoff + (long)(l) * 64 * K + (kg),                       \
         &As[(buf)][(l) * 4096 + w * 512])
#define STAGE_B(l, buf, kg)                                          \
  glds16(BT + boff + (long)(l) * 64 * K + (kg),                      \
         &Bs[(buf)][(l) * 4096 + w * 512])

  const int NT = K >> 6;
  // prologue: tile 0 -> buf 0
#pragma unroll
  for (int l = 0; l < 4; ++l) { STAGE_A(l, 0, 0); STAGE_B(l, 0, 0); }
  asm volatile("s_waitcnt vmcnt(0)" ::: "memory");
  __builtin_amdgcn_sched_barrier(0);
  bar();

  for (int t = 0; t < NT; ++t) {
    const int buf = t & 1;
    if (t + 1 < NT) {
      const long kg = (long)(t + 1) << 6;
#pragma unroll
      for (int l = 0; l < 4; ++l) { STAGE_A(l, buf ^ 1, kg); STAGE_B(l, buf ^ 1, kg); }
    }
    const short* const Asb = As[buf];
    const short* const Bsb = Bs[buf];
    short8 bR[4][2];
#pragma unroll
    for (int j = 0; j < 4; ++j) {
      bR[j][0] = *(const short8*)&Bsb[bbase + j * 1024 + acol0];
      bR[j][1] = *(const short8*)&Bsb[bbase + j * 1024 + acol1];
    }
    __builtin_amdgcn_s_setprio(1);
#pragma unroll
    for (int i = 0; i < 8; ++i) {
      const short8 a0 = *(const short8*)&Asb[abase + i * 1024 + acol0];
      const short8 a1 = *(const short8*)&Asb[abase + i * 1024 + acol1];
#pragma unroll
      for (int j = 0; j < 4; ++j) {
        acc[i][j] = __builtin_amdgcn_mfma_f32_16x16x32_bf16(a0, bR[j][0], acc[i][j], 0, 0, 0);
        acc[i][j] = __builtin_amdgcn_mfma_f32_16x16x32_bf16(a1, bR[j][1], acc[i][j], 0, 0, 0);
      }
    }
    __builtin_amdgcn_s_setprio(0);
    asm volatile("s_waitcnt vmcnt(0)" ::: "memory");
    __builtin_amdgcn_sched_barrier(0);
    bar();
  }

  if constexpr (MODE == 1) {
    const int h = (n0 + wn * 64) >> 6;  // head index in [0,48)
#pragma unroll
    for (int i = 0; i < 8; ++i)
#pragma unroll
      for (int t = 0; t < 4; ++t) {
        const int r = m0 + wm * 128 + i * 16 + g * 4 + t;
        const int s = r & 2047, bb = r >> 11;
        if (h < 40) {
          const float sc = h < 32 ? 0.18033688011112043f : 1.0f;
          short* base = h < 32
              ? Qr + ((long)(bb * 32 + h) * 2048 + s) * 64
              : Kr + ((long)(bb * 8 + (h - 32)) * 2048 + s) * 64;
          const float* cr = cosp + s * 64;
          const float* sr = sinp + s * 64;
#pragma unroll
          for (int j = 0; j < 2; ++j) {
            const int d = j * 16 + lr;
            const float x1 = acc[i][j][t];
            const float x2 = acc[i][j + 2][t];
            base[d] = f2bf((x1 * cr[d] - x2 * sr[d]) * sc);
            base[d + 32] = f2bf((x2 * cr[d + 32] + x1 * sr[d + 32]) * sc);
          }
        } else {
          short* base = YV + ((long)bb * 2048 + s) * 512 + (h - 40) * 64;
#pragma unroll
          for (int j = 0; j < 4; ++j) base[j * 16 + lr] = f2bf(acc[i][j][t]);
        }
      }
  } else {
#pragma unroll
    for (int i = 0; i < 8; ++i)
#pragma unroll
      for (int j = 0; j < 4; ++j)
#pragma unroll
        for (int t = 0; t < 4; ++t) {
          const int r = m0 + wm * 128 + i * 16 + g * 4 + t;
          const int cc = n0 + wn * 64 + j * 16 + lr;
          Cf[(long)r * N + cc] = acc[i][j][t];
        }
  }
#undef STAGE_A
#undef STAGE_B
}

// ---------------------------------------------------------------------------
// Flash attention, transposed formulation, fixed-shift softmax.
// Qr (B,H,S,64) pre-scaled by log2(e)/8, Kr (B,G,S,64), Vt (B,G,64,S).
// Block: 512 thr (8 waves), TWO 128-q tiles per block (QBLK=256) x full S.
// K *and V* fragments register-hoisted out of the qh loop (both are
// q-independent; r7 re-read V per half: 8 wasted ds_read_b128/iter = 29%
// of LDS traffic). KVBLK=64, dbuf staging, counted vmcnt(2). LDS 48 KiB.
// ---------------------------------------------------------------------------
__global__ __launch_bounds__(512, 4) void attn_kernel(
    const short* __restrict__ Qr, const short* __restrict__ Kr,
    const short* __restrict__ Vt, short* __restrict__ Ctx) {
  constexpr int S = 2048;
  constexpr int NIT = 32;
  const int bh = blockIdx.y;
  const int b = bh >> 5, h = bh & 31;
  const int gk = h >> 2;
  const int q0 = blockIdx.x << 8;  // 256 q rows per block
  const int tid = threadIdx.x;
  const int w = tid >> 6, lane = tid & 63;
  const int g = lane >> 4, lr = lane & 15;
  const int b8 = lr & 7;
  const int qrow = w * 16 + lr;

  __shared__ short Ks[2][64 * 64];  // [buf][kv][d], granule swizzle by kv&7
  __shared__ short Vs[2][64 * 64];  // [buf][d][kv], granule swizzle by d&7
  __shared__ short Ps[128 * 64];    // [q][kv],      granule swizzle by q&7

  const short* Qb = Qr + (long)(b * 32 + h) * S * 64;
  const short* Kb = Kr + (long)(b * 8 + gk) * S * 64;
  const short* Vb = Vt + (long)(b * 8 + gk) * 64 * S;

  // LDS read element-offsets
  const int ko0 = lr * 64 + ((0 + g) ^ b8) * 8;  // Ks, kk=0; +i*1024, i<4
  const int ko1 = lr * 64 + ((4 + g) ^ b8) * 8;  // Ks, kk=1
  int vo[2], pr[2], pw[4];
#pragma unroll
  for (int ks = 0; ks < 2; ++ks) {
    vo[ks] = lr * 64 + ((ks * 4 + g) ^ b8) * 8;    // Vs; +di*1024
    pr[ks] = qrow * 64 + ((ks * 4 + g) ^ b8) * 8;  // Ps read
  }
#pragma unroll
  for (int i = 0; i < 4; ++i)
    pw[i] = qrow * 64 + ((2 * i + (g >> 1)) ^ b8) * 8 + (g & 1) * 4;

  // staging: one glds16 each for K and V per iteration (8 KB each).
  const int srow = tid >> 3, sl = tid & 7;
  const long koff = (long)srow * 64 + (sl ^ (srow & 7)) * 8;
  const long voff = (long)srow * S + (sl ^ (srow & 7)) * 8;

  short8 qf[2][2];
#pragma unroll
  for (int qh = 0; qh < 2; ++qh) {
    qf[qh][0] = *(const short8*)&Qb[(long)(q0 + qh * 128 + qrow) * 64 + g * 8];
    qf[qh][1] = *(const short8*)&Qb[(long)(q0 + qh * 128 + qrow) * 64 + 32 + g * 8];
  }

  const short8 ones = (short8)(short)0x3F80;  // bf16 1.0 x8
  float4v lacc[2];
  float4v oacc[2][4];
#pragma unroll
  for (int qh = 0; qh < 2; ++qh) {
    lacc[qh] = (float4v)0.f;
#pragma unroll
    for (int di = 0; di < 4; ++di) oacc[qh][di] = (float4v)0.f;
  }

  // prologue: stage it 0 into buf 0
  glds16(Kb + koff, &Ks[0][w * 512]);
  glds16(Vb + voff, &Vs[0][w * 512]);

  for (int it = 0; it < NIT; ++it) {
    const int buf = it & 1;
    if (it + 1 < NIT) {
      glds16(Kb + (long)(it + 1) * 64 * 64 + koff, &Ks[buf ^ 1][w * 512]);
      glds16(Vb + (it + 1) * 64 + voff, &Vs[buf ^ 1][w * 512]);
      asm volatile("s_waitcnt vmcnt(2)" ::: "memory");  // it's 2 landed
    } else {
      asm volatile("s_waitcnt vmcnt(0)" ::: "memory");
    }
    __builtin_amdgcn_sched_barrier(0);
    bar();

    // K and V fragments are q-independent: hoist once, reuse for both halves.
    short8 kf[8], vf[8];
#pragma unroll
    for (int i = 0; i < 4; ++i) {
      kf[i] = *(const short8*)&Ks[buf][ko0 + i * 1024];
      kf[4 + i] = *(const short8*)&Ks[buf][ko1 + i * 1024];
    }
#pragma unroll
    for (int ks = 0; ks < 2; ++ks)
#pragma unroll
      for (int di = 0; di < 4; ++di)
        vf[ks * 4 + di] = *(const short8*)&Vs[buf][vo[ks] + di * 1024];

#pragma unroll
    for (int qh = 0; qh < 2; ++qh) {
      // S^T tile: rows = kv (64), cols = q (wave strip of 16)
      float4v sacc[4];
#pragma unroll
      for (int i = 0; i < 4; ++i) sacc[i] = (float4v)0.f;
      __builtin_amdgcn_s_setprio(1);
#pragma unroll
      for (int i = 0; i < 4; ++i)
        sacc[i] = __builtin_amdgcn_mfma_f32_16x16x32_bf16(kf[i], qf[qh][0], sacc[i], 0, 0, 0);
#pragma unroll
      for (int i = 0; i < 4; ++i)
        sacc[i] = __builtin_amdgcn_mfma_f32_16x16x32_bf16(kf[4 + i], qf[qh][1], sacc[i], 0, 0, 0);
      __builtin_amdgcn_s_setprio(0);

      // fixed-shift softmax: p = exp2(s) (bare v_exp_f32), pack bf16 -> Ps
      // (r5-proven round-half-up + v_perm_b32 pack)
#pragma unroll
      for (int i = 0; i < 4; ++i) {
        union { float f; unsigned u; } a0, a1, a2, a3;
        a0.f = fexp2(sacc[i][0]);
        a1.f = fexp2(sacc[i][1]);
        a2.f = fexp2(sacc[i][2]);
        a3.f = fexp2(sacc[i][3]);
        const unsigned d0 = __builtin_amdgcn_perm(a1.u + 0x8000u, a0.u + 0x8000u, 0x07060302u);
        const unsigned d1 = __builtin_amdgcn_perm(a3.u + 0x8000u, a2.u + 0x8000u, 0x07060302u);
        *(uint2v*)&Ps[pw[i]] = (uint2v){d0, d1};
      }

      // O^T += V^T * P^T; l += 1^T * P^T (Ps rows wave-private; no barrier)
      __builtin_amdgcn_s_setprio(1);
#pragma unroll
      for (int ks = 0; ks < 2; ++ks) {
        const short8 pf = *(const short8*)&Ps[pr[ks]];
        lacc[qh] = __builtin_amdgcn_mfma_f32_16x16x32_bf16(ones, pf, lacc[qh], 0, 0, 0);
#pragma unroll
        for (int di = 0; di < 4; ++di)
          oacc[qh][di] = __builtin_amdgcn_mfma_f32_16x16x32_bf16(vf[ks * 4 + di], pf, oacc[qh][di], 0, 0, 0);
      }
      __builtin_amdgcn_s_setprio(0);
    }
    bar();  // all waves done reading buf before it+2's DMA can touch it
  }

  // all-ones A => every C row/reg of lacc equals l(q)
#pragma unroll
  for (int qh = 0; qh < 2; ++qh) {
    const float inv = 1.f / lacc[qh][0];
    const int q = q0 + qh * 128 + qrow;
#pragma unroll
    for (int di = 0; di < 4; ++di) {
      short4v o;
#pragma unroll
      for (int t = 0; t < 4; ++t) o[t] = f2bf(oacc[qh][di][t] * inv);
      *(short4v*)&Ctx[(long)(b * S + q) * 2048 + h * 64 + di * 16 + g * 4] = o;
    }
  }
}

// ---------------------------------------------------------------------------
extern "C" void kernel_launch(void* const* d_in, const int* in_sizes, int n_in,
                              void* d_out, int out_size, void* d_ws, size_t ws_size,
                              hipStream_t stream) {
  (void)in_sizes; (void)n_in; (void)out_size; (void)ws_size;
  const float* X    = (const float*)d_in[0];
  const float* cosp = (const float*)d_in[2];
  const float* sinp = (const float*)d_in[3];
  const float* Wq   = (const float*)d_in[4];
  const float* Wk   = (const float*)d_in[5];
  const float* Wv   = (const float*)d_in[6];
  const float* Wo   = (const float*)d_in[7];
  float* out = (float*)d_out;
  char* ws = (char*)d_ws;

  short* Xb = (short*)(ws + 0);           // 16.8 MB bf16 X
  short* WT = (short*)(ws + 16777216);    // 12.6 MB fused QKV^T; reused for Wo^T
  short* Y  = (short*)(ws + 29360128);    // 16.8 MB Ctx (attn out)
  short* Qr = (short*)(ws + 46137344);    // 16.8 MB rope'd Q
  short* Kr = (short*)(ws + 62914560);    // 4.2 MB rope'd K
  short* YV = (short*)(ws + 67108864);    // 4.2 MB compact V (B,S,512)
  short* Vt = (short*)(ws + 71303168);    // 4.2 MB  (total 75.5 MB)

  // fused: X -> bf16 (blocks 0..4095) + QKV W^T (blocks 4096..7167)
  prep<<<7168, 256, 0, stream>>>(X, Xb, Wq, Wk, Wv, WT);

  // fused QKV projection + RoPE + layout: writes Qr, Kr, YV directly
  gemm2<1><<<dim3(12, 16), 512, 0, stream>>>(
      Xb, WT, nullptr, Qr, Kr, YV, cosp, sinp, 4096, 3072, 2048);

  // Wo^T reuses WT (QKV GEMM already consumed it in stream order)
  transpose_f2b<<<dim3(32, 32), 256, 0, stream>>>(Wo, WT, 2048, 2048);

  // V (B,S,512) -> Vt (B,G,64,S)
  vtrans<<<dim3(32, 16), 256, 0, stream>>>(YV, Vt, 512, 0);

  // attention -> Ctx (Y); 512 blocks = 2/CU exactly (QBLK=256)
  attn_kernel<<<dim3(8, 64), 512, 0, stream>>>(Qr, Kr, Vt, Y);

  // output projection (fp32 out)
  gemm2<2><<<dim3(8, 16), 512, 0, stream>>>(
      Y, WT, out, nullptr, nullptr, nullptr, nullptr, nullptr, 4096, 2048, 2048);
}

// Round 9
// 348.463 us; speedup vs baseline: 1.4291x; 1.4291x over previous
//
#include <hip/hip_runtime.h>
#include <stdint.h>

typedef __attribute__((ext_vector_type(8))) short short8;
typedef __attribute__((ext_vector_type(4))) short short4v;
typedef __attribute__((ext_vector_type(4))) float float4v;
typedef __attribute__((ext_vector_type(2))) unsigned uint2v;

__device__ __forceinline__ float bf2f(short s) {
  union { unsigned u; float f; } x;
  x.u = ((unsigned)(unsigned short)s) << 16;
  return x.f;
}
__device__ __forceinline__ short f2bf(float f) {
  union { float f; unsigned u; } x;
  x.f = f;
  unsigned r = x.u + 0x7fffu + ((x.u >> 16) & 1u);
  return (short)(r >> 16);
}
// bare v_exp_f32 — exp2f() calls __ocml_exp2_f32 (range/denorm fixups, ~30
// VALU); our scores are bounded |s|<~50 so the raw HW op is exact.
__device__ __forceinline__ float fexp2(float x) {
#if __has_builtin(__builtin_amdgcn_exp2f)
  return __builtin_amdgcn_exp2f(x);
#else
  float r;
  asm("v_exp_f32 %0, %1" : "=v"(r) : "v"(x));
  return r;
#endif
}
__device__ __forceinline__ void glds16(const void* g, void* l) {
  __builtin_amdgcn_global_load_lds(
      (const __attribute__((address_space(1))) void*)g,
      (__attribute__((address_space(3))) void*)l, 16, 0, 0);
}
__device__ __forceinline__ void bar() { __builtin_amdgcn_s_barrier(); }

// ---------------------------------------------------------------------------
// fp32 transpose -> bf16: src (R x C, f32) -> dst (C x R, bf16), 64x64 tiles.
// ---------------------------------------------------------------------------
__device__ __forceinline__ void transpose_tile(
    const float* __restrict__ src, short* __restrict__ dst, int R, int C,
    int r0, int c0) {
  __shared__ short t[64 * 72];
  const int tid = threadIdx.x;
#pragma unroll
  for (int r = 0; r < 2; ++r) {
    int c = r * 256 + tid;
    int row = c >> 3, col8 = (c & 7) * 8;
    const float4v a = *(const float4v*)&src[(long)(r0 + row) * C + c0 + col8];
    const float4v b = *(const float4v*)&src[(long)(r0 + row) * C + c0 + col8 + 4];
    short8 v;
#pragma unroll
    for (int e = 0; e < 4; ++e) { v[e] = f2bf(a[e]); v[e + 4] = f2bf(b[e]); }
    *(short8*)&t[row * 72 + col8] = v;
  }
  __syncthreads();
#pragma unroll
  for (int r = 0; r < 2; ++r) {
    int c = r * 256 + tid;
    int orow = c >> 3, ocol8 = (c & 7) * 8;
    short8 w;
#pragma unroll
    for (int e = 0; e < 8; ++e) w[e] = t[(ocol8 + e) * 72 + orow];
    *(short8*)&dst[(long)(c0 + orow) * R + r0 + ocol8] = w;
  }
}

// ---------------------------------------------------------------------------
// Fused preprocessing: blocks [0,4096) X f32->bf16; [4096,7168) QKV W^T.
// ---------------------------------------------------------------------------
__global__ __launch_bounds__(256) void prep(
    const float* __restrict__ X, short* __restrict__ Xb,
    const float* __restrict__ Wq, const float* __restrict__ Wk,
    const float* __restrict__ Wv, short* __restrict__ WT) {
  const int id = blockIdx.x;
  if (id < 4096) {
    const long i = ((long)id * 256 + threadIdx.x) * 8;
    const float4v a = *(const float4v*)&X[i];
    const float4v b = *(const float4v*)&X[i + 4];
    short8 v;
#pragma unroll
    for (int e = 0; e < 4; ++e) { v[e] = f2bf(a[e]); v[e + 4] = f2bf(b[e]); }
    *(short8*)&Xb[i] = v;
  } else {
    const int r = id - 4096;
    const int z = r >> 10, bx = r & 31, by = (r >> 5) & 31;
    const float* src = z == 0 ? Wq : (z == 1 ? Wk : Wv);
    const int C = z == 0 ? 2048 : 512;
    if (bx * 64 < C) {
      short* dst = WT + (z == 0 ? 0 : (z == 1 ? 2048 * 2048 : 2560 * 2048));
      transpose_tile(src, dst, 2048, C, by * 64, bx * 64);
    }
  }
}

__global__ __launch_bounds__(256) void transpose_f2b(
    const float* __restrict__ src, short* __restrict__ dst, int R, int C) {
  transpose_tile(src, dst, R, C, blockIdx.y * 64, blockIdx.x * 64);
}

// ---------------------------------------------------------------------------
// V reshape+transpose: YV (B,S,ld) cols [col0, col0+512) bf16 -> Vt (B,G,64,S).
// grid: (S/64, B*G)
// ---------------------------------------------------------------------------
__global__ __launch_bounds__(256) void vtrans(const short* __restrict__ Y,
                                              short* __restrict__ Vt,
                                              int ld, int col0) {
  const int bg = blockIdx.y;
  const int b = bg >> 3, gk = bg & 7;
  const int s0 = blockIdx.x * 64;
  __shared__ short t[64 * 72];
  const int tid = threadIdx.x;
#pragma unroll
  for (int r = 0; r < 2; ++r) {
    int c = r * 256 + tid;
    int row = c >> 3, col8 = (c & 7) * 8;
    short8 v = *(const short8*)&Y[(long)(b * 2048 + s0 + row) * ld + col0 + gk * 64 + col8];
    *(short8*)&t[row * 72 + col8] = v;
  }
  __syncthreads();
#pragma unroll
  for (int r = 0; r < 2; ++r) {
    int c = r * 256 + tid;
    int d = c >> 3, s8 = (c & 7) * 8;
    short8 w;
#pragma unroll
    for (int e = 0; e < 8; ++e) w[e] = t[(s8 + e) * 72 + d];
    *(short8*)&Vt[((long)bg * 64 + d) * 2048 + s0 + s8] = w;
  }
}

// ---------------------------------------------------------------------------
// GEMM: C (MxN) = A (MxK,bf16) * BT (NxK,bf16)^T. 128x128 tile, 4 waves.
// r0/r7-proven structure and block mapping (gemm2 256^2 2-phase REVERTED:
// r8 measured it +21 us vs this — 1 block/CU leaves its vmcnt(0) drain
// unhidden; two structural rewrites have now measured worse, stop).
// MODE 1: fused RoPE/layout epilogue (head = 64-col wave strip):
//   h<32: RoPE+scale -> Qr (B,32,S,64); 32<=h<40: RoPE -> Kr (B,8,S,64);
//   h>=40: plain bf16 -> YV (B,S,512). Rope pair = acc[i][j] / acc[i][j+2].
// MODE 2: plain f32 store.
// ---------------------------------------------------------------------------
template <int MODE>
__global__ __launch_bounds__(256) void gemm_bt(
    const short* __restrict__ A, const short* __restrict__ BT,
    float* __restrict__ Cf, short* __restrict__ Qr, short* __restrict__ Kr,
    short* __restrict__ YV, const float* __restrict__ cosp,
    const float* __restrict__ sinp, int M, int N, int K) {
  (void)M;
  __shared__ short As[128 * 32];
  __shared__ short Bs[128 * 32];
  const int tid = threadIdx.x;
  const int wave = tid >> 6, lane = tid & 63;
  const int g = lane >> 4, lr = lane & 15;
  const int wr = wave >> 1, wc = wave & 1;
  const int m0 = blockIdx.y << 7, n0 = blockIdx.x << 7;

  float4v acc[4][4];
#pragma unroll
  for (int i = 0; i < 4; ++i)
#pragma unroll
    for (int j = 0; j < 4; ++j) acc[i][j] = (float4v)0.f;

  for (int kt = 0; kt < K; kt += 32) {
#pragma unroll
    for (int r = 0; r < 2; ++r) {
      const int cb = r * 256 + wave * 64;
      const int c = cb + lane;
      const int row = c >> 2, kc = c & 3;
      glds16(A + (long)(m0 + row) * K + kt + kc * 8, As + cb * 8);
      glds16(BT + (long)(n0 + row) * K + kt + kc * 8, Bs + cb * 8);
    }
    __syncthreads();
    short8 af[4], bfr[4];
#pragma unroll
    for (int i = 0; i < 4; ++i)
      af[i] = *(const short8*)&As[(wr * 64 + i * 16 + lr) * 32 + g * 8];
#pragma unroll
    for (int j = 0; j < 4; ++j)
      bfr[j] = *(const short8*)&Bs[(wc * 64 + j * 16 + lr) * 32 + g * 8];
#pragma unroll
    for (int i = 0; i < 4; ++i)
#pragma unroll
      for (int j = 0; j < 4; ++j)
        acc[i][j] = __builtin_amdgcn_mfma_f32_16x16x32_bf16(af[i], bfr[j], acc[i][j], 0, 0, 0);
    __syncthreads();
  }

  if constexpr (MODE == 1) {
    const int h = (n0 + wc * 64) >> 6;  // head index in [0,48)
#pragma unroll
    for (int i = 0; i < 4; ++i)
#pragma unroll
      for (int t = 0; t < 4; ++t) {
        const int r = m0 + wr * 64 + i * 16 + g * 4 + t;
        const int s = r & 2047, bb = r >> 11;
        if (h < 40) {
          const float sc = h < 32 ? 0.18033688011112043f : 1.0f;
          short* base = h < 32
              ? Qr + ((long)(bb * 32 + h) * 2048 + s) * 64
              : Kr + ((long)(bb * 8 + (h - 32)) * 2048 + s) * 64;
          const float* cr = cosp + s * 64;
          const float* sr = sinp + s * 64;
#pragma unroll
          for (int j = 0; j < 2; ++j) {
            const int d = j * 16 + lr;
            const float x1 = acc[i][j][t];
            const float x2 = acc[i][j + 2][t];
            base[d] = f2bf((x1 * cr[d] - x2 * sr[d]) * sc);
            base[d + 32] = f2bf((x2 * cr[d + 32] + x1 * sr[d + 32]) * sc);
          }
        } else {
          short* base = YV + ((long)bb * 2048 + s) * 512 + (h - 40) * 64;
#pragma unroll
          for (int j = 0; j < 4; ++j) base[j * 16 + lr] = f2bf(acc[i][j][t]);
        }
      }
  } else {
#pragma unroll
    for (int i = 0; i < 4; ++i)
#pragma unroll
      for (int j = 0; j < 4; ++j)
#pragma unroll
        for (int t = 0; t < 4; ++t) {
          const int r = m0 + wr * 64 + i * 16 + g * 4 + t;
          const int cc = n0 + wc * 64 + j * 16 + lr;
          Cf[(long)r * N + cc] = acc[i][j][t];
        }
  }
}

// ---------------------------------------------------------------------------
// Flash attention, transposed formulation, fixed-shift softmax.
// Qr (B,H,S,64) pre-scaled by log2(e)/8, Kr (B,G,S,64), Vt (B,G,64,S).
// Block: 512 thr (8 waves), TWO 128-q tiles per block (QBLK=256) x full S.
// r8's V-hoist SPILLED (WRITE_SIZE 320 MB of scratch — kf+vf live together
// blew the (512,4) VGPR budget). This version dedups V reads WITHOUT new
// live state: softmax for BOTH q-halves first into a doubled Ps[2] (+16 KB
// LDS, 64 KB total, still 2 blocks/CU), then one combined PV pass where the
// 4 vf fragments are transient in a phase where kf is dead. Max-live equals
// the r7 kernel that ran clean at 90 us. LDS reads 28 -> 20 b128/iter.
// ---------------------------------------------------------------------------
__global__ __launch_bounds__(512, 4) void attn_kernel(
    const short* __restrict__ Qr, const short* __restrict__ Kr,
    const short* __restrict__ Vt, short* __restrict__ Ctx) {
  constexpr int S = 2048;
  constexpr int NIT = 32;
  const int bh = blockIdx.y;
  const int b = bh >> 5, h = bh & 31;
  const int gk = h >> 2;
  const int q0 = blockIdx.x << 8;  // 256 q rows per block
  const int tid = threadIdx.x;
  const int w = tid >> 6, lane = tid & 63;
  const int g = lane >> 4, lr = lane & 15;
  const int b8 = lr & 7;
  const int qrow = w * 16 + lr;

  __shared__ short Ks[2][64 * 64];   // [buf][kv][d], granule swizzle by kv&7
  __shared__ short Vs[2][64 * 64];   // [buf][d][kv], granule swizzle by d&7
  __shared__ short Ps[2][128 * 64];  // [qh][q][kv],  granule swizzle by q&7

  const short* Qb = Qr + (long)(b * 32 + h) * S * 64;
  const short* Kb = Kr + (long)(b * 8 + gk) * S * 64;
  const short* Vb = Vt + (long)(b * 8 + gk) * 64 * S;

  // LDS read element-offsets
  const int ko0 = lr * 64 + ((0 + g) ^ b8) * 8;  // Ks, kk=0; +i*1024, i<4
  const int ko1 = lr * 64 + ((4 + g) ^ b8) * 8;  // Ks, kk=1
  int vo[2], pr[2], pw[4];
#pragma unroll
  for (int ks = 0; ks < 2; ++ks) {
    vo[ks] = lr * 64 + ((ks * 4 + g) ^ b8) * 8;    // Vs; +di*1024
    pr[ks] = qrow * 64 + ((ks * 4 + g) ^ b8) * 8;  // Ps read
  }
#pragma unroll
  for (int i = 0; i < 4; ++i)
    pw[i] = qrow * 64 + ((2 * i + (g >> 1)) ^ b8) * 8 + (g & 1) * 4;

  // staging: one glds16 each for K and V per iteration (8 KB each).
  const int srow = tid >> 3, sl = tid & 7;
  const long koff = (long)srow * 64 + (sl ^ (srow & 7)) * 8;
  const long voff = (long)srow * S + (sl ^ (srow & 7)) * 8;

  short8 qf[2][2];
#pragma unroll
  for (int qh = 0; qh < 2; ++qh) {
    qf[qh][0] = *(const short8*)&Qb[(long)(q0 + qh * 128 + qrow) * 64 + g * 8];
    qf[qh][1] = *(const short8*)&Qb[(long)(q0 + qh * 128 + qrow) * 64 + 32 + g * 8];
  }

  const short8 ones = (short8)(short)0x3F80;  // bf16 1.0 x8
  float4v lacc[2];
  float4v oacc[2][4];
#pragma unroll
  for (int qh = 0; qh < 2; ++qh) {
    lacc[qh] = (float4v)0.f;
#pragma unroll
    for (int di = 0; di < 4; ++di) oacc[qh][di] = (float4v)0.f;
  }

  // prologue: stage it 0 into buf 0
  glds16(Kb + koff, &Ks[0][w * 512]);
  glds16(Vb + voff, &Vs[0][w * 512]);

  for (int it = 0; it < NIT; ++it) {
    const int buf = it & 1;
    if (it + 1 < NIT) {
      glds16(Kb + (long)(it + 1) * 64 * 64 + koff, &Ks[buf ^ 1][w * 512]);
      glds16(Vb + (it + 1) * 64 + voff, &Vs[buf ^ 1][w * 512]);
      asm volatile("s_waitcnt vmcnt(2)" ::: "memory");  // it's 2 landed
    } else {
      asm volatile("s_waitcnt vmcnt(0)" ::: "memory");
    }
    __builtin_amdgcn_sched_barrier(0);
    bar();

    // K fragments are q-independent: hoist once, reuse for both q-halves.
    // (kf dies before the PV pass — vf never coexists with it.)
    short8 kf[8];
#pragma unroll
    for (int i = 0; i < 4; ++i) {
      kf[i] = *(const short8*)&Ks[buf][ko0 + i * 1024];
      kf[4 + i] = *(const short8*)&Ks[buf][ko1 + i * 1024];
    }

    // phase 1: QK^T + softmax for both q-halves -> Ps[qh]
#pragma unroll
    for (int qh = 0; qh < 2; ++qh) {
      float4v sacc[4];
#pragma unroll
      for (int i = 0; i < 4; ++i) sacc[i] = (float4v)0.f;
      __builtin_amdgcn_s_setprio(1);
#pragma unroll
      for (int i = 0; i < 4; ++i)
        sacc[i] = __builtin_amdgcn_mfma_f32_16x16x32_bf16(kf[i], qf[qh][0], sacc[i], 0, 0, 0);
#pragma unroll
      for (int i = 0; i < 4; ++i)
        sacc[i] = __builtin_amdgcn_mfma_f32_16x16x32_bf16(kf[4 + i], qf[qh][1], sacc[i], 0, 0, 0);
      __builtin_amdgcn_s_setprio(0);

      // fixed-shift softmax: p = exp2(s), r5-proven round-half-up + perm pack
#pragma unroll
      for (int i = 0; i < 4; ++i) {
        union { float f; unsigned u; } a0, a1, a2, a3;
        a0.f = fexp2(sacc[i][0]);
        a1.f = fexp2(sacc[i][1]);
        a2.f = fexp2(sacc[i][2]);
        a3.f = fexp2(sacc[i][3]);
        const unsigned d0 = __builtin_amdgcn_perm(a1.u + 0x8000u, a0.u + 0x8000u, 0x07060302u);
        const unsigned d1 = __builtin_amdgcn_perm(a3.u + 0x8000u, a2.u + 0x8000u, 0x07060302u);
        *(uint2v*)&Ps[qh][pw[i]] = (uint2v){d0, d1};
      }
    }

    // phase 2: combined PV — each vf fragment read ONCE, used by both halves
    // (Ps rows wave-private; LDS ops in-order per wave -> no barrier needed)
    __builtin_amdgcn_s_setprio(1);
#pragma unroll
    for (int ks = 0; ks < 2; ++ks) {
      short8 vf[4];
#pragma unroll
      for (int di = 0; di < 4; ++di)
        vf[di] = *(const short8*)&Vs[buf][vo[ks] + di * 1024];
#pragma unroll
      for (int qh = 0; qh < 2; ++qh) {
        const short8 pf = *(const short8*)&Ps[qh][pr[ks]];
        lacc[qh] = __builtin_amdgcn_mfma_f32_16x16x32_bf16(ones, pf, lacc[qh], 0, 0, 0);
#pragma unroll
        for (int di = 0; di < 4; ++di)
          oacc[qh][di] = __builtin_amdgcn_mfma_f32_16x16x32_bf16(vf[di], pf, oacc[qh][di], 0, 0, 0);
      }
    }
    __builtin_amdgcn_s_setprio(0);
    bar();  // all waves done reading buf before it+2's DMA can touch it
  }

  // all-ones A => every C row/reg of lacc equals l(q)
#pragma unroll
  for (int qh = 0; qh < 2; ++qh) {
    const float inv = 1.f / lacc[qh][0];
    const int q = q0 + qh * 128 + qrow;
#pragma unroll
    for (int di = 0; di < 4; ++di) {
      short4v o;
#pragma unroll
      for (int t = 0; t < 4; ++t) o[t] = f2bf(oacc[qh][di][t] * inv);
      *(short4v*)&Ctx[(long)(b * S + q) * 2048 + h * 64 + di * 16 + g * 4] = o;
    }
  }
}

// ---------------------------------------------------------------------------
extern "C" void kernel_launch(void* const* d_in, const int* in_sizes, int n_in,
                              void* d_out, int out_size, void* d_ws, size_t ws_size,
                              hipStream_t stream) {
  (void)in_sizes; (void)n_in; (void)out_size; (void)ws_size;
  const float* X    = (const float*)d_in[0];
  const float* cosp = (const float*)d_in[2];
  const float* sinp = (const float*)d_in[3];
  const float* Wq   = (const float*)d_in[4];
  const float* Wk   = (const float*)d_in[5];
  const float* Wv   = (const float*)d_in[6];
  const float* Wo   = (const float*)d_in[7];
  float* out = (float*)d_out;
  char* ws = (char*)d_ws;

  short* Xb = (short*)(ws + 0);           // 16.8 MB bf16 X
  short* WT = (short*)(ws + 16777216);    // 12.6 MB fused QKV^T; reused for Wo^T
  short* Y  = (short*)(ws + 29360128);    // 16.8 MB Ctx (attn out)
  short* Qr = (short*)(ws + 46137344);    // 16.8 MB rope'd Q
  short* Kr = (short*)(ws + 62914560);    // 4.2 MB rope'd K
  short* YV = (short*)(ws + 67108864);    // 4.2 MB compact V (B,S,512)
  short* Vt = (short*)(ws + 71303168);    // 4.2 MB  (total 75.5 MB)

  // fused: X -> bf16 (blocks 0..4095) + QKV W^T (blocks 4096..7167)
  prep<<<7168, 256, 0, stream>>>(X, Xb, Wq, Wk, Wv, WT);

  // fused QKV projection + RoPE + layout: writes Qr, Kr, YV directly
  gemm_bt<1><<<dim3(24, 32), 256, 0, stream>>>(
      Xb, WT, nullptr, Qr, Kr, YV, cosp, sinp, 4096, 3072, 2048);

  // Wo^T reuses WT (QKV GEMM already consumed it in stream order)
  transpose_f2b<<<dim3(32, 32), 256, 0, stream>>>(Wo, WT, 2048, 2048);

  // V (B,S,512) -> Vt (B,G,64,S)
  vtrans<<<dim3(32, 16), 256, 0, stream>>>(YV, Vt, 512, 0);

  // attention -> Ctx (Y); 512 blocks = 2/CU exactly (QBLK=256)
  attn_kernel<<<dim3(8, 64), 512, 0, stream>>>(Qr, Kr, Vt, Y);

  // output projection (fp32 out)
  gemm_bt<2><<<dim3(16, 32), 256, 0, stream>>>(
      Y, WT, out, nullptr, nullptr, nullptr, nullptr, nullptr, 4096, 2048, 2048);
}